// Round 9
// baseline (497.232 us; speedup 1.0000x reference)
//
#include <hip/hip_runtime.h>
#include <hip/hip_fp16.h>

#define NN 50000
#define EE 800000

typedef float f32x4 __attribute__((ext_vector_type(4)));
typedef _Float16 f16x8 __attribute__((ext_vector_type(8)));
typedef _Float16 f16x4 __attribute__((ext_vector_type(4)));
typedef _Float16 f16x2 __attribute__((ext_vector_type(2)));

// ---------------------------------------------------------------------------
// CSR build
// ---------------------------------------------------------------------------
__global__ void hist_kernel(const int* __restrict__ dst, int* __restrict__ counts, int E) {
    int idx = blockIdx.x * blockDim.x + threadIdx.x;
    int stride = gridDim.x * blockDim.x;
    for (int e = idx; e < E; e += stride)
        atomicAdd(&counts[dst[e]], 1);
}

__global__ void scan_phaseA(const int* __restrict__ counts, int* __restrict__ bsum, int n) {
    __shared__ int buf[256];
    int b = blockIdx.x, t = threadIdx.x;
    int i = b * 256 + t;
    buf[t] = (i < n) ? counts[i] : 0;
    __syncthreads();
#pragma unroll
    for (int off = 128; off; off >>= 1) {
        if (t < off) buf[t] += buf[t + off];
        __syncthreads();
    }
    if (t == 0) bsum[b] = buf[0];
}

__global__ void scan_phaseB(int* __restrict__ bsum, int* __restrict__ row_off_n, int nb) {
    __shared__ int buf[256];
    int t = threadIdx.x;
    int v = (t < nb) ? bsum[t] : 0;
    buf[t] = v;
    __syncthreads();
#pragma unroll
    for (int off = 1; off < 256; off <<= 1) {
        int x = (t >= off) ? buf[t - off] : 0;
        __syncthreads();
        buf[t] += x;
        __syncthreads();
    }
    if (t < nb) bsum[t] = buf[t] - v;       // exclusive block offset
    if (t == 255) *row_off_n = buf[255];    // total -> row_off[N]
}

__global__ void scan_phaseC(const int* __restrict__ counts, const int* __restrict__ bsum,
                            int* __restrict__ row_off, int n) {
    __shared__ int buf[256];
    int b = blockIdx.x, t = threadIdx.x;
    int i = b * 256 + t;
    int v = (i < n) ? counts[i] : 0;
    buf[t] = v;
    __syncthreads();
#pragma unroll
    for (int off = 1; off < 256; off <<= 1) {
        int x = (t >= off) ? buf[t - off] : 0;
        __syncthreads();
        buf[t] += x;
        __syncthreads();
    }
    if (i < n) row_off[i] = bsum[b] + buf[t] - v;
}

__global__ void scatter_kernel(const int* __restrict__ src, const int* __restrict__ dst,
                               const int* __restrict__ row_off, int* __restrict__ cursor,
                               int* __restrict__ esrc, int E) {
    int idx = blockIdx.x * blockDim.x + threadIdx.x;
    int stride = gridDim.x * blockDim.x;
    for (int e = idx; e < E; e += stride) {
        int d = dst[e];
        int pos = row_off[d] + atomicAdd(&cursor[d], 1);
        esrc[pos] = src[e];
    }
}

// ---------------------------------------------------------------------------
// Fused prep: weights -> FRAGMENT-READY fp16 layout, x -> fp16.
// ---------------------------------------------------------------------------
__device__ __forceinline__ void wfrag_store(__half* o, int K, int col, int k, float v) {
    int KS = K >> 5;
    int cgni = col >> 4, l15 = col & 15;
    int ks = k >> 5, qq = (k >> 3) & 3, ee = k & 7;
    size_t flat = ((size_t)(cgni * KS + ks) * 64 + qq * 16 + l15) * 8 + ee;
    o[flat] = __float2half_rn(v);
}

__global__ void prep_all(const float* __restrict__ Wl1, const float* __restrict__ Wr1,
                         const float* __restrict__ Wl2, const float* __restrict__ Wr2,
                         const float* __restrict__ Wl3, const float* __restrict__ Wr3,
                         const float* __restrict__ Wlin,
                         __half* __restrict__ w1, __half* __restrict__ w2,
                         __half* __restrict__ w3, __half* __restrict__ w4,
                         const float* __restrict__ x, __half* __restrict__ xf, int n4x) {
    int idx = blockIdx.x * blockDim.x + threadIdx.x;
    if (idx < 233472) {
        const float* W; __half* o; int K, Nc, roff, li;
        if (idx < 65536) {
            K = 128; Nc = 256; o = w1;
            if (idx < 32768) { W = Wl1; li = idx; roff = 0; }
            else             { W = Wr1; li = idx - 32768; roff = 256; }
        } else if (idx < 196608) {
            K = 256; Nc = 256; o = w2;
            if (idx < 131072) { W = Wl2; li = idx - 65536; roff = 0; }
            else              { W = Wr2; li = idx - 131072; roff = 256; }
        } else if (idx < 229376) {
            K = 256; Nc = 64; o = w3;
            if (idx < 212992) { W = Wl3; li = idx - 196608; roff = 0; }
            else              { W = Wr3; li = idx - 212992; roff = 64; }
        } else {
            K = 64; Nc = 64; o = w4; W = Wlin; li = idx - 229376; roff = 0;
        }
        int k = li / Nc, n = li - k * Nc;
        wfrag_store(o, K, roff + n, k, W[li]);
    } else {
        int xi = idx - 233472;
        if (xi < n4x) {
            float4 v = *(const float4*)(x + (size_t)xi * 4);
            f16x4 h = {(_Float16)v.x, (_Float16)v.y, (_Float16)v.z, (_Float16)v.w};
            *(f16x4*)((_Float16*)xf + (size_t)xi * 4) = h;
        }
    }
}

// ---------------------------------------------------------------------------
// Weight-stationary tall-skinny GEMM. NBX>0: XCD-aware swizzle of a logical
// (NBX x 4) grid -- the 4 column-blocks sharing a row-tile get the same
// bid%8 (same XCD) so A-tile re-reads hit that XCD's L2.
// ---------------------------------------------------------------------------
template <int KS, int COLG, int NBX>
__global__ __launch_bounds__(COLG * 256) void gemm_ws(
        const __half* __restrict__ A, const __half* __restrict__ Bt,
        int M, int nTiles, int Nc, int splitCol,
        __half* __restrict__ outL, __half* __restrict__ outR,
        float* __restrict__ outF, const float* __restrict__ bias) {
    constexpr int K = KS * 32;
    int tid = threadIdx.x;
    int lane = tid & 63;
    int w = tid >> 6;
    int rs = w & 3;
    int cg = w >> 2;
    int l15 = lane & 15, q = lane >> 4;

    int bx, by;
    if constexpr (NBX > 0) {
        int bid = blockIdx.x;
        by = (bid >> 3) & 3;                       // logical column block 0..3
        bx = ((bid >> 5) << 3) | (bid & 7);        // same bx -> same bid%8 (XCD)
    } else {
        bx = blockIdx.x; by = blockIdx.y;
    }
    const int gstride = (NBX > 0) ? NBX : gridDim.x;

    int colbase = by * (COLG * 64) + cg * 64;

    const _Float16* Ap = (const _Float16*)A;
    const f16x8* Bf = (const f16x8*)Bt;
    int cgni0 = (by * COLG + cg) * 4;

    f16x8 bfrag[KS][4];
#pragma unroll
    for (int ks = 0; ks < KS; ++ks)
#pragma unroll
        for (int ni = 0; ni < 4; ++ni)
            bfrag[ks][ni] = Bf[((size_t)(cgni0 + ni) * KS + ks) * 64 + lane];

    int tile = bx;
    if (tile >= nTiles) return;

    f16x8 afrag[KS];
    {
        int row = tile * 64 + rs * 16 + l15;
        if (row >= M) row = M - 1;
        const _Float16* ap = Ap + (size_t)row * K + q * 8;
#pragma unroll
        for (int ks = 0; ks < KS; ++ks) afrag[ks] = *(const f16x8*)(ap + ks * 32);
    }

    while (true) {
        int next = tile + gstride;
        bool has = (next < nTiles);
        f16x8 anext[KS];
        if (has) {
            int row = next * 64 + rs * 16 + l15;
            if (row >= M) row = M - 1;
            const _Float16* ap = Ap + (size_t)row * K + q * 8;
#pragma unroll
            for (int ks = 0; ks < KS; ++ks) anext[ks] = *(const f16x8*)(ap + ks * 32);
        }

        f32x4 acc[4] = {};
#pragma unroll
        for (int ks = 0; ks < KS; ++ks)
#pragma unroll
            for (int ni = 0; ni < 4; ++ni)
                acc[ni] = __builtin_amdgcn_mfma_f32_16x16x32_f16(afrag[ks], bfrag[ks][ni], acc[ni], 0, 0, 0);

#pragma unroll
        for (int ni = 0; ni < 4; ++ni) {
            int gc = colbase + ni * 16 + l15;
            if (outF) {
                float bv = bias ? bias[gc] : 0.f;
#pragma unroll
                for (int r = 0; r < 4; ++r) {
                    int gr = tile * 64 + rs * 16 + q * 4 + r;
                    if (gr < M) outF[(size_t)gr * Nc + gc] = acc[ni][r] + bv;
                }
            } else {
                __half* dp = outL; int cc = gc;
                if (gc >= splitCol) { dp = outR; cc = gc - splitCol; }
#pragma unroll
                for (int r = 0; r < 4; ++r) {
                    int gr = tile * 64 + rs * 16 + q * 4 + r;
                    if (gr < M) dp[(size_t)gr * splitCol + cc] = __float2half_rn(acc[ni][r]);
                }
            }
        }
        if (!has) break;
#pragma unroll
        for (int ks = 0; ks < KS; ++ks) afrag[ks] = anext[ks];
        tile = next;
    }
}

// ---------------------------------------------------------------------------
// DPP helpers: butterfly adds on the VALU pipe.
// ---------------------------------------------------------------------------
template <int CTRL>
__device__ __forceinline__ float dpp_add_f32(float x) {
    int y = __builtin_amdgcn_mov_dpp(__float_as_int(x), CTRL, 0xF, 0xF, true);
    return x + __int_as_float(y);
}

// raw v_exp_f32 (= 2^x), with s_nop hazard guard for the trans-op result
__device__ __forceinline__ float fast_exp2(float x) {
    float r;
    asm("v_exp_f32 %0, %1\n\ts_nop 0" : "=v"(r) : "v"(x));
    return r;
}

// ---------------------------------------------------------------------------
// GATv2 gather, H=4 x C=64. R20: R18 structure (32 lanes/edge x 2 slots,
// 4-deep copy-free rotation, 128-thr blocks) with ALL CLAMPS REMOVED:
//   - esrc is padded with 128 zero ints past E. Any esrc value is a valid
//     node id and p=0 predication kills out-of-row contributions, so the
//     min(idx,elast) chain (~6 ops of the ~40-op phase) was semantically
//     redundant. Gather is issue-bound (R19: depth/block matrix all ~65.5us,
//     VALUBusy 65%) -> fewer instructions is the remaining lever.
// ---------------------------------------------------------------------------
__global__ __launch_bounds__(128, 8) void gat_gather_h4(
        const __half* __restrict__ xl, const __half* __restrict__ xr,
        const float* __restrict__ att, const float* __restrict__ bias,
        const int* __restrict__ row_off, const int* __restrict__ esrc,
        __half* __restrict__ out, int n) {
    const float LOG2E = 1.44269504f;
    int wave = threadIdx.x >> 6;
    int lane = threadIdx.x & 63;
    int node = blockIdx.x * 2 + wave;
    if (node >= n) return;
    int slot = lane >> 5;         // 0..1 : which edge of the phase
    unsigned jj = lane & 31;      // channels 8*jj .. 8*jj+7

    const uint4* xl16 = (const uint4*)xl;   // 32 uint4 per row

    f16x2 xrv[4];
    *(uint4*)(&xrv[0]) = ((const uint4*)xr)[((unsigned)node << 5) + jj];

    float4 a0 = *(const float4*)(att + jj * 8);
    float4 a1 = *(const float4*)(att + jj * 8 + 4);
    f16x2 atv[4] = {
        {(_Float16)(a0.x * LOG2E), (_Float16)(a0.y * LOG2E)},
        {(_Float16)(a0.z * LOG2E), (_Float16)(a0.w * LOG2E)},
        {(_Float16)(a1.x * LOG2E), (_Float16)(a1.y * LOG2E)},
        {(_Float16)(a1.z * LOG2E), (_Float16)(a1.w * LOG2E)}};
    const f16x2 k02 = {(_Float16)0.2f, (_Float16)0.2f};

    float acc[8] = {};
    float L = 0.f;

    int e0 = row_off[node], e1 = row_off[node + 1];

    // prologue: srcs + 4 gathers covering edges e0 .. e0+7 (esrc padded)
    int sA = esrc[e0 + 0 + slot];
    int sB = esrc[e0 + 2 + slot];
    int sC = esrc[e0 + 4 + slot];
    int sD = esrc[e0 + 6 + slot];
    uint4 A = xl16[((unsigned)sA << 5) + jj];
    uint4 B = xl16[((unsigned)sB << 5) + jj];
    uint4 C = xl16[((unsigned)sC << 5) + jj];
    uint4 D = xl16[((unsigned)sD << 5) + jj];

#define H4_PHASE(BUF, EB)                                                     \
    {                                                                         \
        f16x2 v[4];                                                           \
        *(uint4*)(&v[0]) = BUF;                                               \
        float t = 0.f;                                                        \
        _Pragma("unroll")                                                     \
        for (int k = 0; k < 4; ++k) {                                         \
            f16x2 s = v[k] + xrv[k];                                          \
            f16x2 r = __builtin_elementwise_max(s, s * k02);                  \
            t = __builtin_amdgcn_fdot2(r, atv[k], t, false);                  \
        }                                                                     \
        t = dpp_add_f32<0xB1>(t);                                             \
        t = dpp_add_f32<0x4E>(t);                                             \
        t = dpp_add_f32<0x141>(t);                                            \
        float p = fast_exp2(t);                                               \
        p = ((EB) + slot < e1) ? p : 0.f;                                     \
        L += p;                                                               \
        _Pragma("unroll")                                                     \
        for (int k = 0; k < 4; ++k) {                                         \
            acc[2 * k]     = fmaf((float)v[k].x, p, acc[2 * k]);              \
            acc[2 * k + 1] = fmaf((float)v[k].y, p, acc[2 * k + 1]);          \
        }                                                                     \
    }

    {
        int e = e0;
        while (true) {
            int ns = esrc[e + 8 + slot];
            H4_PHASE(A, e)
            A = xl16[((unsigned)ns << 5) + jj];
            e += 2; if (e >= e1) break;
            ns = esrc[e + 8 + slot];
            H4_PHASE(B, e)
            B = xl16[((unsigned)ns << 5) + jj];
            e += 2; if (e >= e1) break;
            ns = esrc[e + 8 + slot];
            H4_PHASE(C, e)
            C = xl16[((unsigned)ns << 5) + jj];
            e += 2; if (e >= e1) break;
            ns = esrc[e + 8 + slot];
            H4_PHASE(D, e)
            D = xl16[((unsigned)ns << 5) + jj];
            e += 2; if (e >= e1) break;
        }
    }
#undef H4_PHASE

    // reduce partial sums across the 2 edge-slots (once per node)
#pragma unroll
    for (int k = 0; k < 8; ++k) acc[k] += __shfl_xor(acc[k], 32);
    L += __shfl_xor(L, 32);

    if (slot == 0) {
        float inv = 1.f / (L + 1e-16f);
        float4 b0 = *(const float4*)(bias + jj * 8);
        float4 b1v = *(const float4*)(bias + jj * 8 + 4);
        float bb[8] = {b0.x, b0.y, b0.z, b0.w, b1v.x, b1v.y, b1v.z, b1v.w};
        f16x8 o0;
#pragma unroll
        for (int k = 0; k < 8; ++k) {
            float vA = acc[k] * inv + bb[k];
            vA = vA > 0.f ? vA : __expf(vA) - 1.f;   // ELU
            o0[k] = (_Float16)vA;
        }
        *(f16x8*)((_Float16*)out + ((size_t)node << 8) + jj * 8) = o0;
    }
}

// ---------------------------------------------------------------------------
// GATv2 gather, H=1 x C=64 (no ELU). 8 lanes/edge x 8 slots, 3-deep
// copy-free rotation, clamps removed (padded esrc), 128-thread blocks.
// ---------------------------------------------------------------------------
__global__ __launch_bounds__(128, 8) void gat_gather_h1(
        const __half* __restrict__ xl, const __half* __restrict__ xr,
        const float* __restrict__ att, const float* __restrict__ bias,
        const int* __restrict__ row_off, const int* __restrict__ esrc,
        __half* __restrict__ out, int n) {
    const float LOG2E = 1.44269504f;
    int wave = threadIdx.x >> 6;
    int lane = threadIdx.x & 63;
    int node = blockIdx.x * 2 + wave;
    if (node >= n) return;
    int eslot = lane >> 3;        // 0..7
    unsigned j = lane & 7;        // channels 8j .. 8j+7

    const uint4* xl16 = (const uint4*)xl;   // 8 uint4 per row

    f16x2 xrv[4];
    *(uint4*)(&xrv[0]) = ((const uint4*)xr)[((unsigned)node << 3) + j];

    float4 a0 = *(const float4*)(att + j * 8);
    float4 a1 = *(const float4*)(att + j * 8 + 4);
    f16x2 atv[4] = {
        {(_Float16)(a0.x * LOG2E), (_Float16)(a0.y * LOG2E)},
        {(_Float16)(a0.z * LOG2E), (_Float16)(a0.w * LOG2E)},
        {(_Float16)(a1.x * LOG2E), (_Float16)(a1.y * LOG2E)},
        {(_Float16)(a1.z * LOG2E), (_Float16)(a1.w * LOG2E)}};
    const f16x2 k02 = {(_Float16)0.2f, (_Float16)0.2f};

    float acc[8] = {};
    float L = 0.f;

    int e0 = row_off[node], e1 = row_off[node + 1];

    // prologue: srcs + 3 gathers for edges e0 .. e0+23 (esrc padded)
    int sA = esrc[e0 +  0 + eslot];
    int sB = esrc[e0 +  8 + eslot];
    int sC = esrc[e0 + 16 + eslot];
    uint4 A = xl16[((unsigned)sA << 3) + j];
    uint4 B = xl16[((unsigned)sB << 3) + j];
    uint4 C = xl16[((unsigned)sC << 3) + j];

#define H1_PHASE(R, EB)                                                       \
    {                                                                         \
        f16x2 v[4];                                                           \
        *(uint4*)(&v[0]) = R;                                                 \
        float t0 = 0.f, t1 = 0.f;                                             \
        {                                                                     \
            f16x2 s0 = v[0] + xrv[0];                                         \
            f16x2 r0 = __builtin_elementwise_max(s0, s0 * k02);               \
            t0 = __builtin_amdgcn_fdot2(r0, atv[0], t0, false);               \
            f16x2 s1 = v[1] + xrv[1];                                         \
            f16x2 r1 = __builtin_elementwise_max(s1, s1 * k02);               \
            t0 = __builtin_amdgcn_fdot2(r1, atv[1], t0, false);               \
            f16x2 s2 = v[2] + xrv[2];                                         \
            f16x2 r2 = __builtin_elementwise_max(s2, s2 * k02);               \
            t1 = __builtin_amdgcn_fdot2(r2, atv[2], t1, false);               \
            f16x2 s3 = v[3] + xrv[3];                                         \
            f16x2 r3 = __builtin_elementwise_max(s3, s3 * k02);               \
            t1 = __builtin_amdgcn_fdot2(r3, atv[3], t1, false);               \
        }                                                                     \
        float t = t0 + t1;                                                    \
        t = dpp_add_f32<0xB1>(t);                                             \
        t = dpp_add_f32<0x4E>(t);                                             \
        t = dpp_add_f32<0x141>(t);                                            \
        float p = fast_exp2(t);                                               \
        p = ((EB) + eslot < e1) ? p : 0.f;                                    \
        L += p;                                                               \
        _Pragma("unroll")                                                     \
        for (int k = 0; k < 4; ++k) {                                         \
            acc[2 * k]     = fmaf((float)v[k].x, p, acc[2 * k]);              \
            acc[2 * k + 1] = fmaf((float)v[k].y, p, acc[2 * k + 1]);          \
        }                                                                     \
    }

    {
        int e = e0;
        while (true) {
            int ns = esrc[e + 24 + eslot];
            H1_PHASE(A, e)
            A = xl16[((unsigned)ns << 3) + j];
            e += 8; if (e >= e1) break;
            ns = esrc[e + 24 + eslot];
            H1_PHASE(B, e)
            B = xl16[((unsigned)ns << 3) + j];
            e += 8; if (e >= e1) break;
            ns = esrc[e + 24 + eslot];
            H1_PHASE(C, e)
            C = xl16[((unsigned)ns << 3) + j];
            e += 8; if (e >= e1) break;
        }
    }
#undef H1_PHASE

    // reduce partial sums across the 8 edge-slots
#pragma unroll
    for (int k = 0; k < 8; ++k) {
        acc[k] += __shfl_xor(acc[k], 8);
        acc[k] += __shfl_xor(acc[k], 16);
        acc[k] += __shfl_xor(acc[k], 32);
    }
    L += __shfl_xor(L, 8);
    L += __shfl_xor(L, 16);
    L += __shfl_xor(L, 32);

    if (eslot == 0) {
        float inv = 1.f / (L + 1e-16f);
        float4 b0 = *(const float4*)(bias + j * 8);
        float4 b1v = *(const float4*)(bias + j * 8 + 4);
        float bb[8] = {b0.x, b0.y, b0.z, b0.w, b1v.x, b1v.y, b1v.z, b1v.w};
        f16x8 ov;
#pragma unroll
        for (int k = 0; k < 8; ++k)
            ov[k] = (_Float16)(acc[k] * inv + bb[k]);
        *(f16x8*)((_Float16*)out + ((size_t)node << 6) + j * 8) = ov;
    }
}

// ---------------------------------------------------------------------------
extern "C" void kernel_launch(void* const* d_in, const int* in_sizes, int n_in,
                              void* d_out, int out_size, void* d_ws, size_t ws_size,
                              hipStream_t stream) {
    const float* x    = (const float*)d_in[0];
    const float* Wl1  = (const float*)d_in[1];
    const float* Wr1  = (const float*)d_in[2];
    const float* att1 = (const float*)d_in[3];
    const float* b1   = (const float*)d_in[4];
    const float* Wl2  = (const float*)d_in[5];
    const float* Wr2  = (const float*)d_in[6];
    const float* att2 = (const float*)d_in[7];
    const float* b2   = (const float*)d_in[8];
    const float* Wl3  = (const float*)d_in[9];
    const float* Wr3  = (const float*)d_in[10];
    const float* att3 = (const float*)d_in[11];
    const float* b3   = (const float*)d_in[12];
    const float* Wlin = (const float*)d_in[13];
    const float* blin = (const float*)d_in[14];
    const int*   ei   = (const int*)d_in[15];
    const int* src = ei;
    const int* dst = ei + EE;

    const int N = NN, E = EE;
    const int NB = (N + 255) / 256;             // 196 scan blocks

    __half* xf = (__half*)d_ws;                 // N*128
    __half* xl = xf + (size_t)N * 128;          // N*256
    __half* xr = xl + (size_t)N * 256;          // N*256
    __half* H  = xr + (size_t)N * 256;          // N*256
    __half* G  = H + (size_t)N * 256;           // N*64
    __half* w1 = G + (size_t)N * 64;            // 65536  frag-layout
    __half* w2 = w1 + 65536;                    // 131072
    __half* w3 = w2 + 131072;                   // 32768
    __half* w4 = w3 + 32768;                    // 4096
    int* row_off = (int*)(w4 + 4096);           // N+1
    int* tmp     = row_off + (N + 1);           // 2N (counts | cursor)
    int* esrc    = tmp + 2 * N;                 // E + 128 (PADDED: declamped
                                                //   gather prologue/refills
                                                //   read up to esrc[E+40])
    int* bsum    = esrc + E + 128;              // 256

    // --- build CSR by dst ---
    hipMemsetAsync(tmp, 0, (size_t)2 * N * sizeof(int), stream);
    hipMemsetAsync(esrc + E, 0, 128 * sizeof(int), stream);   // zero the pad
    hist_kernel<<<1024, 256, 0, stream>>>(dst, tmp, E);
    scan_phaseA<<<NB, 256, 0, stream>>>(tmp, bsum, N);
    scan_phaseB<<<1, 256, 0, stream>>>(bsum, row_off + N, NB);
    scan_phaseC<<<NB, 256, 0, stream>>>(tmp, bsum, row_off, N);
    scatter_kernel<<<1024, 256, 0, stream>>>(src, dst, row_off, tmp + N, esrc, E);

    // --- weights (fragment layout) + x -> fp16 ---
    int n4x = N * 128 / 4;
    prep_all<<<(233472 + n4x + 255) / 256, 256, 0, stream>>>(
        Wl1, Wr1, Wl2, Wr2, Wl3, Wr3, Wlin, w1, w2, w3, w4, x, xf, n4x);

    int nTiles = (N + 63) / 64;                 // 782
    int gatherBlocks = (N + 1) / 2;             // 128-thread blocks, 2 nodes

    // --- layer 1: xf[128] @ w1 -> xl,xr fp16 (XCD-swizzled 128x4 grid) ---
    gemm_ws<4, 2, 128><<<512, 512, 0, stream>>>(
        xf, w1, N, nTiles, 512, 256, xl, xr, nullptr, nullptr);
    gat_gather_h4<<<gatherBlocks, 128, 0, stream>>>(xl, xr, att1, b1, row_off, esrc, H, N);

    // --- layer 2: H[256] @ w2 -> xl,xr (XCD-swizzled 128x4 grid) ---
    gemm_ws<8, 2, 128><<<512, 512, 0, stream>>>(
        H, w2, N, nTiles, 512, 256, xl, xr, nullptr, nullptr);
    gat_gather_h4<<<gatherBlocks, 128, 0, stream>>>(xl, xr, att2, b2, row_off, esrc, H, N);

    // --- layer 3: H[256] @ w3 -> xl,xr ([N][64] each) ---
    gemm_ws<8, 2, 0><<<dim3(256, 1), 512, 0, stream>>>(
        H, w3, N, nTiles, 128, 64, xl, xr, nullptr, nullptr);
    gat_gather_h1<<<gatherBlocks, 128, 0, stream>>>(xl, xr, att3, b3, row_off, esrc, G, N);

    // --- final: G[64] @ w4 + blin -> d_out fp32 ---
    gemm_ws<2, 1, 0><<<dim3(512, 1), 256, 0, stream>>>(
        G, w4, N, nTiles, 64, 64, nullptr, nullptr, (float*)d_out, blin);
}

// Round 10
// 456.156 us; speedup vs baseline: 1.0900x; 1.0900x over previous
//
#include <hip/hip_runtime.h>
#include <hip/hip_fp16.h>

#define NN 50000
#define EE 800000

typedef float f32x4 __attribute__((ext_vector_type(4)));
typedef _Float16 f16x8 __attribute__((ext_vector_type(8)));
typedef _Float16 f16x4 __attribute__((ext_vector_type(4)));
typedef _Float16 f16x2 __attribute__((ext_vector_type(2)));

// ---------------------------------------------------------------------------
// CSR build
// ---------------------------------------------------------------------------
__global__ void hist_kernel(const int* __restrict__ dst, int* __restrict__ counts, int E) {
    int idx = blockIdx.x * blockDim.x + threadIdx.x;
    int stride = gridDim.x * blockDim.x;
    for (int e = idx; e < E; e += stride)
        atomicAdd(&counts[dst[e]], 1);
}

__global__ void scan_phaseA(const int* __restrict__ counts, int* __restrict__ bsum, int n) {
    __shared__ int buf[256];
    int b = blockIdx.x, t = threadIdx.x;
    int i = b * 256 + t;
    buf[t] = (i < n) ? counts[i] : 0;
    __syncthreads();
#pragma unroll
    for (int off = 128; off; off >>= 1) {
        if (t < off) buf[t] += buf[t + off];
        __syncthreads();
    }
    if (t == 0) bsum[b] = buf[0];
}

__global__ void scan_phaseB(int* __restrict__ bsum, int* __restrict__ row_off_n, int nb) {
    __shared__ int buf[256];
    int t = threadIdx.x;
    int v = (t < nb) ? bsum[t] : 0;
    buf[t] = v;
    __syncthreads();
#pragma unroll
    for (int off = 1; off < 256; off <<= 1) {
        int x = (t >= off) ? buf[t - off] : 0;
        __syncthreads();
        buf[t] += x;
        __syncthreads();
    }
    if (t < nb) bsum[t] = buf[t] - v;       // exclusive block offset
    if (t == 255) *row_off_n = buf[255];    // total -> row_off[N]
}

__global__ void scan_phaseC(const int* __restrict__ counts, const int* __restrict__ bsum,
                            int* __restrict__ row_off, int n) {
    __shared__ int buf[256];
    int b = blockIdx.x, t = threadIdx.x;
    int i = b * 256 + t;
    int v = (i < n) ? counts[i] : 0;
    buf[t] = v;
    __syncthreads();
#pragma unroll
    for (int off = 1; off < 256; off <<= 1) {
        int x = (t >= off) ? buf[t - off] : 0;
        __syncthreads();
        buf[t] += x;
        __syncthreads();
    }
    if (i < n) row_off[i] = bsum[b] + buf[t] - v;
}

__global__ void scatter_kernel(const int* __restrict__ src, const int* __restrict__ dst,
                               const int* __restrict__ row_off, int* __restrict__ cursor,
                               int* __restrict__ esrc, int E) {
    int idx = blockIdx.x * blockDim.x + threadIdx.x;
    int stride = gridDim.x * blockDim.x;
    for (int e = idx; e < E; e += stride) {
        int d = dst[e];
        int pos = row_off[d] + atomicAdd(&cursor[d], 1);
        esrc[pos] = src[e];
    }
}

// ---------------------------------------------------------------------------
// Fused prep: weights -> FRAGMENT-READY fp16 layout, x -> fp16.
// ---------------------------------------------------------------------------
__device__ __forceinline__ void wfrag_store(__half* o, int K, int col, int k, float v) {
    int KS = K >> 5;
    int cgni = col >> 4, l15 = col & 15;
    int ks = k >> 5, qq = (k >> 3) & 3, ee = k & 7;
    size_t flat = ((size_t)(cgni * KS + ks) * 64 + qq * 16 + l15) * 8 + ee;
    o[flat] = __float2half_rn(v);
}

__global__ void prep_all(const float* __restrict__ Wl1, const float* __restrict__ Wr1,
                         const float* __restrict__ Wl2, const float* __restrict__ Wr2,
                         const float* __restrict__ Wl3, const float* __restrict__ Wr3,
                         const float* __restrict__ Wlin,
                         __half* __restrict__ w1, __half* __restrict__ w2,
                         __half* __restrict__ w3, __half* __restrict__ w4,
                         const float* __restrict__ x, __half* __restrict__ xf, int n4x) {
    int idx = blockIdx.x * blockDim.x + threadIdx.x;
    if (idx < 233472) {
        const float* W; __half* o; int K, Nc, roff, li;
        if (idx < 65536) {
            K = 128; Nc = 256; o = w1;
            if (idx < 32768) { W = Wl1; li = idx; roff = 0; }
            else             { W = Wr1; li = idx - 32768; roff = 256; }
        } else if (idx < 196608) {
            K = 256; Nc = 256; o = w2;
            if (idx < 131072) { W = Wl2; li = idx - 65536; roff = 0; }
            else              { W = Wr2; li = idx - 131072; roff = 256; }
        } else if (idx < 229376) {
            K = 256; Nc = 64; o = w3;
            if (idx < 212992) { W = Wl3; li = idx - 196608; roff = 0; }
            else              { W = Wr3; li = idx - 212992; roff = 64; }
        } else {
            K = 64; Nc = 64; o = w4; W = Wlin; li = idx - 229376; roff = 0;
        }
        int k = li / Nc, n = li - k * Nc;
        wfrag_store(o, K, roff + n, k, W[li]);
    } else {
        int xi = idx - 233472;
        if (xi < n4x) {
            float4 v = *(const float4*)(x + (size_t)xi * 4);
            f16x4 h = {(_Float16)v.x, (_Float16)v.y, (_Float16)v.z, (_Float16)v.w};
            *(f16x4*)((_Float16*)xf + (size_t)xi * 4) = h;
        }
    }
}

// ---------------------------------------------------------------------------
// Weight-stationary tall-skinny GEMM. NBX>0: XCD-aware swizzle of a logical
// (NBX x 4) grid -- the 4 column-blocks sharing a row-tile get the same
// bid%8 (same XCD) so A-tile re-reads hit that XCD's L2.
// ---------------------------------------------------------------------------
template <int KS, int COLG, int NBX>
__global__ __launch_bounds__(COLG * 256) void gemm_ws(
        const __half* __restrict__ A, const __half* __restrict__ Bt,
        int M, int nTiles, int Nc, int splitCol,
        __half* __restrict__ outL, __half* __restrict__ outR,
        float* __restrict__ outF, const float* __restrict__ bias) {
    constexpr int K = KS * 32;
    int tid = threadIdx.x;
    int lane = tid & 63;
    int w = tid >> 6;
    int rs = w & 3;
    int cg = w >> 2;
    int l15 = lane & 15, q = lane >> 4;

    int bx, by;
    if constexpr (NBX > 0) {
        int bid = blockIdx.x;
        by = (bid >> 3) & 3;                       // logical column block 0..3
        bx = ((bid >> 5) << 3) | (bid & 7);        // same bx -> same bid%8 (XCD)
    } else {
        bx = blockIdx.x; by = blockIdx.y;
    }
    const int gstride = (NBX > 0) ? NBX : gridDim.x;

    int colbase = by * (COLG * 64) + cg * 64;

    const _Float16* Ap = (const _Float16*)A;
    const f16x8* Bf = (const f16x8*)Bt;
    int cgni0 = (by * COLG + cg) * 4;

    f16x8 bfrag[KS][4];
#pragma unroll
    for (int ks = 0; ks < KS; ++ks)
#pragma unroll
        for (int ni = 0; ni < 4; ++ni)
            bfrag[ks][ni] = Bf[((size_t)(cgni0 + ni) * KS + ks) * 64 + lane];

    int tile = bx;
    if (tile >= nTiles) return;

    f16x8 afrag[KS];
    {
        int row = tile * 64 + rs * 16 + l15;
        if (row >= M) row = M - 1;
        const _Float16* ap = Ap + (size_t)row * K + q * 8;
#pragma unroll
        for (int ks = 0; ks < KS; ++ks) afrag[ks] = *(const f16x8*)(ap + ks * 32);
    }

    while (true) {
        int next = tile + gstride;
        bool has = (next < nTiles);
        f16x8 anext[KS];
        if (has) {
            int row = next * 64 + rs * 16 + l15;
            if (row >= M) row = M - 1;
            const _Float16* ap = Ap + (size_t)row * K + q * 8;
#pragma unroll
            for (int ks = 0; ks < KS; ++ks) anext[ks] = *(const f16x8*)(ap + ks * 32);
        }

        f32x4 acc[4] = {};
#pragma unroll
        for (int ks = 0; ks < KS; ++ks)
#pragma unroll
            for (int ni = 0; ni < 4; ++ni)
                acc[ni] = __builtin_amdgcn_mfma_f32_16x16x32_f16(afrag[ks], bfrag[ks][ni], acc[ni], 0, 0, 0);

#pragma unroll
        for (int ni = 0; ni < 4; ++ni) {
            int gc = colbase + ni * 16 + l15;
            if (outF) {
                float bv = bias ? bias[gc] : 0.f;
#pragma unroll
                for (int r = 0; r < 4; ++r) {
                    int gr = tile * 64 + rs * 16 + q * 4 + r;
                    if (gr < M) outF[(size_t)gr * Nc + gc] = acc[ni][r] + bv;
                }
            } else {
                __half* dp = outL; int cc = gc;
                if (gc >= splitCol) { dp = outR; cc = gc - splitCol; }
#pragma unroll
                for (int r = 0; r < 4; ++r) {
                    int gr = tile * 64 + rs * 16 + q * 4 + r;
                    if (gr < M) dp[(size_t)gr * splitCol + cc] = __float2half_rn(acc[ni][r]);
                }
            }
        }
        if (!has) break;
#pragma unroll
        for (int ks = 0; ks < KS; ++ks) afrag[ks] = anext[ks];
        tile = next;
    }
}

// ---------------------------------------------------------------------------
// DPP helpers: butterfly adds on the VALU pipe.
// ---------------------------------------------------------------------------
template <int CTRL>
__device__ __forceinline__ float dpp_add_f32(float x) {
    int y = __builtin_amdgcn_mov_dpp(__float_as_int(x), CTRL, 0xF, 0xF, true);
    return x + __int_as_float(y);
}

// raw v_exp_f32 (= 2^x), with s_nop hazard guard for the trans-op result
__device__ __forceinline__ float fast_exp2(float x) {
    float r;
    asm("v_exp_f32 %0, %1\n\ts_nop 0" : "=v"(r) : "v"(x));
    return r;
}

// ---------------------------------------------------------------------------
// GATv2 gather, H=4 x C=64. R21 = R18 exact revert (best verified, 65.4us):
// 32 lanes/edge x 2 slots, 4-deep copy-free rotation, CLAMPED refills
// (min(idx,elast) makes tail refills L1 hits on the hot elast row -- R20
// showed declamping costs +43% FETCH and +26% time), per-2-edge early exit,
// 128-thread blocks.
// ---------------------------------------------------------------------------
__global__ __launch_bounds__(128, 8) void gat_gather_h4(
        const __half* __restrict__ xl, const __half* __restrict__ xr,
        const float* __restrict__ att, const float* __restrict__ bias,
        const int* __restrict__ row_off, const int* __restrict__ esrc,
        __half* __restrict__ out, int n) {
    const float LOG2E = 1.44269504f;
    int wave = threadIdx.x >> 6;
    int lane = threadIdx.x & 63;
    int node = blockIdx.x * 2 + wave;
    if (node >= n) return;
    int slot = lane >> 5;         // 0..1 : which edge of the phase
    unsigned jj = lane & 31;      // channels 8*jj .. 8*jj+7

    const uint4* xl16 = (const uint4*)xl;   // 32 uint4 per row

    f16x2 xrv[4];
    *(uint4*)(&xrv[0]) = ((const uint4*)xr)[((unsigned)node << 5) + jj];

    float4 a0 = *(const float4*)(att + jj * 8);
    float4 a1 = *(const float4*)(att + jj * 8 + 4);
    f16x2 atv[4] = {
        {(_Float16)(a0.x * LOG2E), (_Float16)(a0.y * LOG2E)},
        {(_Float16)(a0.z * LOG2E), (_Float16)(a0.w * LOG2E)},
        {(_Float16)(a1.x * LOG2E), (_Float16)(a1.y * LOG2E)},
        {(_Float16)(a1.z * LOG2E), (_Float16)(a1.w * LOG2E)}};
    const f16x2 k02 = {(_Float16)0.2f, (_Float16)0.2f};

    float acc[8] = {};
    float L = 0.f;

    int e0 = row_off[node], e1 = row_off[node + 1];
    int elast = (e1 > e0) ? e1 - 1 : 0;

    // prologue: srcs + 4 gathers covering edges e0 .. e0+7
    int sA = esrc[min(e0 + 0 + slot, elast)];
    int sB = esrc[min(e0 + 2 + slot, elast)];
    int sC = esrc[min(e0 + 4 + slot, elast)];
    int sD = esrc[min(e0 + 6 + slot, elast)];
    uint4 A = xl16[((unsigned)sA << 5) + jj];
    uint4 B = xl16[((unsigned)sB << 5) + jj];
    uint4 C = xl16[((unsigned)sC << 5) + jj];
    uint4 D = xl16[((unsigned)sD << 5) + jj];

#define H4_PHASE(BUF, EB)                                                     \
    {                                                                         \
        f16x2 v[4];                                                           \
        *(uint4*)(&v[0]) = BUF;                                               \
        float t = 0.f;                                                        \
        _Pragma("unroll")                                                     \
        for (int k = 0; k < 4; ++k) {                                         \
            f16x2 s = v[k] + xrv[k];                                          \
            f16x2 r = __builtin_elementwise_max(s, s * k02);                  \
            t = __builtin_amdgcn_fdot2(r, atv[k], t, false);                  \
        }                                                                     \
        t = dpp_add_f32<0xB1>(t);                                             \
        t = dpp_add_f32<0x4E>(t);                                             \
        t = dpp_add_f32<0x141>(t);                                            \
        float p = fast_exp2(t);                                               \
        p = ((EB) + slot < e1) ? p : 0.f;                                     \
        L += p;                                                               \
        _Pragma("unroll")                                                     \
        for (int k = 0; k < 4; ++k) {                                         \
            acc[2 * k]     = fmaf((float)v[k].x, p, acc[2 * k]);              \
            acc[2 * k + 1] = fmaf((float)v[k].y, p, acc[2 * k + 1]);          \
        }                                                                     \
    }

    {
        int e = e0;
        while (true) {
            int ns = esrc[min(e + 8 + slot, elast)];
            H4_PHASE(A, e)
            A = xl16[((unsigned)ns << 5) + jj];
            e += 2; if (e >= e1) break;
            ns = esrc[min(e + 8 + slot, elast)];
            H4_PHASE(B, e)
            B = xl16[((unsigned)ns << 5) + jj];
            e += 2; if (e >= e1) break;
            ns = esrc[min(e + 8 + slot, elast)];
            H4_PHASE(C, e)
            C = xl16[((unsigned)ns << 5) + jj];
            e += 2; if (e >= e1) break;
            ns = esrc[min(e + 8 + slot, elast)];
            H4_PHASE(D, e)
            D = xl16[((unsigned)ns << 5) + jj];
            e += 2; if (e >= e1) break;
        }
    }
#undef H4_PHASE

    // reduce partial sums across the 2 edge-slots (once per node)
#pragma unroll
    for (int k = 0; k < 8; ++k) acc[k] += __shfl_xor(acc[k], 32);
    L += __shfl_xor(L, 32);

    if (slot == 0) {
        float inv = 1.f / (L + 1e-16f);
        float4 b0 = *(const float4*)(bias + jj * 8);
        float4 b1v = *(const float4*)(bias + jj * 8 + 4);
        float bb[8] = {b0.x, b0.y, b0.z, b0.w, b1v.x, b1v.y, b1v.z, b1v.w};
        f16x8 o0;
#pragma unroll
        for (int k = 0; k < 8; ++k) {
            float vA = acc[k] * inv + bb[k];
            vA = vA > 0.f ? vA : __expf(vA) - 1.f;   // ELU
            o0[k] = (_Float16)vA;
        }
        *(f16x8*)((_Float16*)out + ((size_t)node << 8) + jj * 8) = o0;
    }
}

// ---------------------------------------------------------------------------
// GATv2 gather, H=1 x C=64 (no ELU). 8 lanes/edge x 8 slots, 3-deep
// copy-free rotation, clamped refills, per-phase early exit, 128-thr blocks.
// ---------------------------------------------------------------------------
__global__ __launch_bounds__(128, 8) void gat_gather_h1(
        const __half* __restrict__ xl, const __half* __restrict__ xr,
        const float* __restrict__ att, const float* __restrict__ bias,
        const int* __restrict__ row_off, const int* __restrict__ esrc,
        __half* __restrict__ out, int n) {
    const float LOG2E = 1.44269504f;
    int wave = threadIdx.x >> 6;
    int lane = threadIdx.x & 63;
    int node = blockIdx.x * 2 + wave;
    if (node >= n) return;
    int eslot = lane >> 3;        // 0..7
    unsigned j = lane & 7;        // channels 8j .. 8j+7

    const uint4* xl16 = (const uint4*)xl;   // 8 uint4 per row

    f16x2 xrv[4];
    *(uint4*)(&xrv[0]) = ((const uint4*)xr)[((unsigned)node << 3) + j];

    float4 a0 = *(const float4*)(att + j * 8);
    float4 a1 = *(const float4*)(att + j * 8 + 4);
    f16x2 atv[4] = {
        {(_Float16)(a0.x * LOG2E), (_Float16)(a0.y * LOG2E)},
        {(_Float16)(a0.z * LOG2E), (_Float16)(a0.w * LOG2E)},
        {(_Float16)(a1.x * LOG2E), (_Float16)(a1.y * LOG2E)},
        {(_Float16)(a1.z * LOG2E), (_Float16)(a1.w * LOG2E)}};
    const f16x2 k02 = {(_Float16)0.2f, (_Float16)0.2f};

    float acc[8] = {};
    float L = 0.f;

    int e0 = row_off[node], e1 = row_off[node + 1];
    int elast = (e1 > e0) ? e1 - 1 : 0;

    // prologue: srcs + 3 gathers for edges e0 .. e0+23
    int sA = esrc[min(e0 +  0 + eslot, elast)];
    int sB = esrc[min(e0 +  8 + eslot, elast)];
    int sC = esrc[min(e0 + 16 + eslot, elast)];
    uint4 A = xl16[((unsigned)sA << 3) + j];
    uint4 B = xl16[((unsigned)sB << 3) + j];
    uint4 C = xl16[((unsigned)sC << 3) + j];

#define H1_PHASE(R, EB)                                                       \
    {                                                                         \
        f16x2 v[4];                                                           \
        *(uint4*)(&v[0]) = R;                                                 \
        float t0 = 0.f, t1 = 0.f;                                             \
        {                                                                     \
            f16x2 s0 = v[0] + xrv[0];                                         \
            f16x2 r0 = __builtin_elementwise_max(s0, s0 * k02);               \
            t0 = __builtin_amdgcn_fdot2(r0, atv[0], t0, false);               \
            f16x2 s1 = v[1] + xrv[1];                                         \
            f16x2 r1 = __builtin_elementwise_max(s1, s1 * k02);               \
            t0 = __builtin_amdgcn_fdot2(r1, atv[1], t0, false);               \
            f16x2 s2 = v[2] + xrv[2];                                         \
            f16x2 r2 = __builtin_elementwise_max(s2, s2 * k02);               \
            t1 = __builtin_amdgcn_fdot2(r2, atv[2], t1, false);               \
            f16x2 s3 = v[3] + xrv[3];                                         \
            f16x2 r3 = __builtin_elementwise_max(s3, s3 * k02);               \
            t1 = __builtin_amdgcn_fdot2(r3, atv[3], t1, false);               \
        }                                                                     \
        float t = t0 + t1;                                                    \
        t = dpp_add_f32<0xB1>(t);                                             \
        t = dpp_add_f32<0x4E>(t);                                             \
        t = dpp_add_f32<0x141>(t);                                            \
        float p = fast_exp2(t);                                               \
        p = ((EB) + eslot < e1) ? p : 0.f;                                    \
        L += p;                                                               \
        _Pragma("unroll")                                                     \
        for (int k = 0; k < 4; ++k) {                                         \
            acc[2 * k]     = fmaf((float)v[k].x, p, acc[2 * k]);              \
            acc[2 * k + 1] = fmaf((float)v[k].y, p, acc[2 * k + 1]);          \
        }                                                                     \
    }

    {
        int e = e0;
        while (true) {
            int ns = esrc[min(e + 24 + eslot, elast)];
            H1_PHASE(A, e)
            A = xl16[((unsigned)ns << 3) + j];
            e += 8; if (e >= e1) break;
            ns = esrc[min(e + 24 + eslot, elast)];
            H1_PHASE(B, e)
            B = xl16[((unsigned)ns << 3) + j];
            e += 8; if (e >= e1) break;
            ns = esrc[min(e + 24 + eslot, elast)];
            H1_PHASE(C, e)
            C = xl16[((unsigned)ns << 3) + j];
            e += 8; if (e >= e1) break;
        }
    }
#undef H1_PHASE

    // reduce partial sums across the 8 edge-slots
#pragma unroll
    for (int k = 0; k < 8; ++k) {
        acc[k] += __shfl_xor(acc[k], 8);
        acc[k] += __shfl_xor(acc[k], 16);
        acc[k] += __shfl_xor(acc[k], 32);
    }
    L += __shfl_xor(L, 8);
    L += __shfl_xor(L, 16);
    L += __shfl_xor(L, 32);

    if (eslot == 0) {
        float inv = 1.f / (L + 1e-16f);
        float4 b0 = *(const float4*)(bias + j * 8);
        float4 b1v = *(const float4*)(bias + j * 8 + 4);
        float bb[8] = {b0.x, b0.y, b0.z, b0.w, b1v.x, b1v.y, b1v.z, b1v.w};
        f16x8 ov;
#pragma unroll
        for (int k = 0; k < 8; ++k)
            ov[k] = (_Float16)(acc[k] * inv + bb[k]);
        *(f16x8*)((_Float16*)out + ((size_t)node << 6) + j * 8) = ov;
    }
}

// ---------------------------------------------------------------------------
extern "C" void kernel_launch(void* const* d_in, const int* in_sizes, int n_in,
                              void* d_out, int out_size, void* d_ws, size_t ws_size,
                              hipStream_t stream) {
    const float* x    = (const float*)d_in[0];
    const float* Wl1  = (const float*)d_in[1];
    const float* Wr1  = (const float*)d_in[2];
    const float* att1 = (const float*)d_in[3];
    const float* b1   = (const float*)d_in[4];
    const float* Wl2  = (const float*)d_in[5];
    const float* Wr2  = (const float*)d_in[6];
    const float* att2 = (const float*)d_in[7];
    const float* b2   = (const float*)d_in[8];
    const float* Wl3  = (const float*)d_in[9];
    const float* Wr3  = (const float*)d_in[10];
    const float* att3 = (const float*)d_in[11];
    const float* b3   = (const float*)d_in[12];
    const float* Wlin = (const float*)d_in[13];
    const float* blin = (const float*)d_in[14];
    const int*   ei   = (const int*)d_in[15];
    const int* src = ei;
    const int* dst = ei + EE;

    const int N = NN, E = EE;
    const int NB = (N + 255) / 256;             // 196 scan blocks

    __half* xf = (__half*)d_ws;                 // N*128
    __half* xl = xf + (size_t)N * 128;          // N*256
    __half* xr = xl + (size_t)N * 256;          // N*256
    __half* H  = xr + (size_t)N * 256;          // N*256
    __half* G  = H + (size_t)N * 256;           // N*64
    __half* w1 = G + (size_t)N * 64;            // 65536  frag-layout
    __half* w2 = w1 + 65536;                    // 131072
    __half* w3 = w2 + 131072;                   // 32768
    __half* w4 = w3 + 32768;                    // 4096
    int* row_off = (int*)(w4 + 4096);           // N+1
    int* tmp     = row_off + (N + 1);           // 2N (counts | cursor)
    int* esrc    = tmp + 2 * N;                 // E
    int* bsum    = esrc + E;                    // 256

    // --- build CSR by dst ---
    hipMemsetAsync(tmp, 0, (size_t)2 * N * sizeof(int), stream);
    hist_kernel<<<1024, 256, 0, stream>>>(dst, tmp, E);
    scan_phaseA<<<NB, 256, 0, stream>>>(tmp, bsum, N);
    scan_phaseB<<<1, 256, 0, stream>>>(bsum, row_off + N, NB);
    scan_phaseC<<<NB, 256, 0, stream>>>(tmp, bsum, row_off, N);
    scatter_kernel<<<1024, 256, 0, stream>>>(src, dst, row_off, tmp + N, esrc, E);

    // --- weights (fragment layout) + x -> fp16 ---
    int n4x = N * 128 / 4;
    prep_all<<<(233472 + n4x + 255) / 256, 256, 0, stream>>>(
        Wl1, Wr1, Wl2, Wr2, Wl3, Wr3, Wlin, w1, w2, w3, w4, x, xf, n4x);

    int nTiles = (N + 63) / 64;                 // 782
    int gatherBlocks = (N + 1) / 2;             // 128-thread blocks, 2 nodes

    // --- layer 1: xf[128] @ w1 -> xl,xr fp16 (XCD-swizzled 128x4 grid) ---
    gemm_ws<4, 2, 128><<<512, 512, 0, stream>>>(
        xf, w1, N, nTiles, 512, 256, xl, xr, nullptr, nullptr);
    gat_gather_h4<<<gatherBlocks, 128, 0, stream>>>(xl, xr, att1, b1, row_off, esrc, H, N);

    // --- layer 2: H[256] @ w2 -> xl,xr (XCD-swizzled 128x4 grid) ---
    gemm_ws<8, 2, 128><<<512, 512, 0, stream>>>(
        H, w2, N, nTiles, 512, 256, xl, xr, nullptr, nullptr);
    gat_gather_h4<<<gatherBlocks, 128, 0, stream>>>(xl, xr, att2, b2, row_off, esrc, H, N);

    // --- layer 3: H[256] @ w3 -> xl,xr ([N][64] each) ---
    gemm_ws<8, 2, 0><<<dim3(256, 1), 512, 0, stream>>>(
        H, w3, N, nTiles, 128, 64, xl, xr, nullptr, nullptr);
    gat_gather_h1<<<gatherBlocks, 128, 0, stream>>>(xl, xr, att3, b3, row_off, esrc, G, N);

    // --- final: G[64] @ w4 + blin -> d_out fp32 ---
    gemm_ws<2, 1, 0><<<dim3(512, 1), 256, 0, stream>>>(
        G, w4, N, nTiles, 64, 64, nullptr, nullptr, (float*)d_out, blin);
}